// Round 3
// baseline (9595.861 us; speedup 1.0000x reference)
//
#include <hip/hip_runtime.h>
#include <math.h>

#define NB   8
#define CI   64
#define COC  64
#define HQ   256
#define HK   64
#define KS   5
#define LL   256
#define NBIJ 1600
#define NPAD 1664

// ---------------- conv 3x3 pad1 + bias + leaky relu (NCHW) ----------------
// block (W/4, 256/(W/4)); grid (1, H/blockDim.y, N*CO); thread -> 4 x-outputs
__global__ __launch_bounds__(256) void conv3_lrelu(
    const float* __restrict__ in, const float* __restrict__ Wt,
    const float* __restrict__ bias, float* __restrict__ out, int H, int Wd) {
  const int x0 = threadIdx.x * 4;
  const int y  = blockIdx.y * blockDim.y + threadIdx.y;
  const int z  = blockIdx.z;
  const int n  = z / COC;
  const int co = z % COC;
  const float* wbase = Wt + co * CI * 9;
  float4 acc = make_float4(0.f, 0.f, 0.f, 0.f);
  #pragma unroll 2
  for (int ci = 0; ci < CI; ++ci) {
    const float* ib = in + ((size_t)(n * CI + ci) * H) * Wd;
    const float* wp = wbase + ci * 9;
    #pragma unroll
    for (int ky = 0; ky < 3; ++ky) {
      const int yy = y + ky - 1;
      float v0, v1, v2, v3, v4, v5;
      if (yy >= 0 && yy < H) {
        const float* row = ib + (size_t)yy * Wd + x0;
        float4 m = *(const float4*)row;
        v1 = m.x; v2 = m.y; v3 = m.z; v4 = m.w;
        v0 = (x0 > 0) ? row[-1] : 0.f;
        v5 = (x0 + 4 < Wd) ? row[4] : 0.f;
      } else {
        v0 = v1 = v2 = v3 = v4 = v5 = 0.f;
      }
      const float wa = wp[ky * 3 + 0], wb = wp[ky * 3 + 1], wc = wp[ky * 3 + 2];
      acc.x = fmaf(wa, v0, fmaf(wb, v1, fmaf(wc, v2, acc.x)));
      acc.y = fmaf(wa, v1, fmaf(wb, v2, fmaf(wc, v3, acc.y)));
      acc.z = fmaf(wa, v2, fmaf(wb, v3, fmaf(wc, v4, acc.z)));
      acc.w = fmaf(wa, v3, fmaf(wb, v4, fmaf(wc, v5, acc.w)));
    }
  }
  const float bv = bias[co];
  float4 o;
  float t;
  t = acc.x + bv; o.x = t > 0.f ? t : 0.01f * t;
  t = acc.y + bv; o.y = t > 0.f ? t : 0.01f * t;
  t = acc.z + bv; o.z = t > 0.f ? t : 0.01f * t;
  t = acc.w + bv; o.w = t > 0.f ? t : 0.01f * t;
  *(float4*)(out + ((size_t)(n * COC + co) * H + y) * Wd + x0) = o;
}

// ---------------- k-patch squared norms ----------------
// grid (LL, N), block 64 (one thread per channel)
__global__ void knorm_kernel(const float* __restrict__ kfea, float* __restrict__ norms) {
  const int l = blockIdx.x, n = blockIdx.y, c = threadIdx.x;
  const int ly = l >> 4, lx = l & 15;
  const float* base = kfea + ((size_t)(n * CI + c) * HK) * HK;
  float ss = 0.f;
  #pragma unroll
  for (int i = 0; i < KS; ++i) {
    const int r = 4 * ly + i;
    if (r >= HK) continue;
    #pragma unroll
    for (int j = 0; j < KS; ++j) {
      const int cc = 4 * lx + j;
      if (cc >= HK) continue;
      const float v = base[r * HK + cc];
      ss = fmaf(v, v, ss);
    }
  }
  for (int off = 32; off; off >>= 1) ss += __shfl_down(ss, off);
  if (c == 0) norms[n * LL + l] = ss;
}

// grid N, block 256
__global__ void kscale_kernel(const float* __restrict__ norms, float* __restrict__ kscale) {
  const int n = blockIdx.x, t = threadIdx.x;
  float v = norms[n * LL + t];
  for (int off = 32; off; off >>= 1) v = fmaxf(v, __shfl_down(v, off));
  __shared__ float red[4];
  if ((t & 63) == 0) red[t >> 6] = v;
  __syncthreads();
  if (t == 0) {
    const float m = fmaxf(fmaxf(red[0], red[1]), fmaxf(red[2], red[3]));
    kscale[n] = 10.0f / sqrtf(m);
  }
}

// ---------------- fused QK correlation + softmax ----------------
// grid (64 h, N); block 256. Computes wn[n][h][w=0..63][l=0..255].
__global__ __launch_bounds__(256) void qk_softmax(
    const float* __restrict__ qfea, const float* __restrict__ kfea,
    const float* __restrict__ kscale, float* __restrict__ wn) {
  const int h = blockIdx.x, n = blockIdx.y;
  const int tid = threadIdx.x;
  const int lt = tid >> 4;   // ly (0..15)
  const int wt = tid & 15;   // w group: w = wt*4+ww
  __shared__ float k_s[25 * 16 * 16];
  __shared__ float q_s[25 * 64];
  __shared__ float red[64 * 17];
  float acc[16][4];
  #pragma unroll
  for (int a = 0; a < 16; ++a)
    #pragma unroll
    for (int b = 0; b < 4; ++b) acc[a][b] = 0.f;

  const float* kb = kfea + (size_t)n * CI * HK * HK;
  const float* qb = qfea + (size_t)n * CI * HQ * HQ;

  for (int ci = 0; ci < CI; ++ci) {
    __syncthreads();
    for (int s = tid; s < 25 * 256; s += 256) {
      const int lx = s & 15, ly = (s >> 4) & 15, ij = s >> 8;
      const int i = ij / 5, j = ij % 5;
      const int r = 4 * ly + i, c = 4 * lx + j;
      k_s[s] = (r < HK && c < HK) ? kb[((size_t)ci * HK + r) * HK + c] : 0.f;
    }
    for (int s = tid; s < 25 * 64; s += 256) {
      const int w = s & 63, ij = s >> 6;
      const int i = ij / 5, j = ij % 5;
      const int gr = 4 * h + i, gc = 4 * w + j;
      q_s[s] = (gr < HQ && gc < HQ) ? qb[((size_t)ci * HQ + gr) * HQ + gc] : 0.f;
    }
    __syncthreads();
    #pragma unroll 5
    for (int ij = 0; ij < 25; ++ij) {
      const float4 q4 = *(const float4*)&q_s[ij * 64 + wt * 4];
      const float4* kp4 = (const float4*)&k_s[(ij * 16 + lt) * 16];
      const float4 k0 = kp4[0], k1 = kp4[1], k2 = kp4[2], k3 = kp4[3];
      const float kk[16] = {k0.x, k0.y, k0.z, k0.w, k1.x, k1.y, k1.z, k1.w,
                            k2.x, k2.y, k2.z, k2.w, k3.x, k3.y, k3.z, k3.w};
      const float qq[4] = {q4.x, q4.y, q4.z, q4.w};
      #pragma unroll
      for (int li = 0; li < 16; ++li)
        #pragma unroll
        for (int ww = 0; ww < 4; ++ww)
          acc[li][ww] = fmaf(kk[li], qq[ww], acc[li][ww]);
    }
  }

  const float f = kscale[n];
  #pragma unroll
  for (int li = 0; li < 16; ++li)
    #pragma unroll
    for (int ww = 0; ww < 4; ++ww) acc[li][ww] *= f;

  // row max over l (per w)
  #pragma unroll
  for (int ww = 0; ww < 4; ++ww) {
    float m = acc[0][ww];
    #pragma unroll
    for (int li = 1; li < 16; ++li) m = fmaxf(m, acc[li][ww]);
    red[(wt * 4 + ww) * 17 + lt] = m;
  }
  __syncthreads();
  if (tid < 64) {
    float m = red[tid * 17];
    #pragma unroll
    for (int k = 1; k < 16; ++k) m = fmaxf(m, red[tid * 17 + k]);
    red[tid * 17 + 16] = m;
  }
  __syncthreads();
  float sloc[4];
  #pragma unroll
  for (int ww = 0; ww < 4; ++ww) {
    const float m = red[(wt * 4 + ww) * 17 + 16];
    float s = 0.f;
    #pragma unroll
    for (int li = 0; li < 16; ++li) {
      const float e = __expf(acc[li][ww] - m);
      acc[li][ww] = e;
      s += e;
    }
    sloc[ww] = s;
  }
  __syncthreads();
  #pragma unroll
  for (int ww = 0; ww < 4; ++ww) red[(wt * 4 + ww) * 17 + lt] = sloc[ww];
  __syncthreads();
  if (tid < 64) {
    float s = red[tid * 17];
    #pragma unroll
    for (int k = 1; k < 16; ++k) s += red[tid * 17 + k];
    red[tid * 17 + 16] = s;
  }
  __syncthreads();
  #pragma unroll
  for (int ww = 0; ww < 4; ++ww) {
    const int w = wt * 4 + ww;
    const float inv = 1.0f / red[w * 17 + 16];
    float* dst = wn + (((size_t)(n * 64 + h) * 64 + w) * 256) + lt * 16;
    #pragma unroll
    for (int q = 0; q < 4; ++q) {
      float4 o = make_float4(acc[q * 4 + 0][ww] * inv, acc[q * 4 + 1][ww] * inv,
                             acc[q * 4 + 2][ww] * inv, acc[q * 4 + 3][ww] * inv);
      *(float4*)(dst + q * 4) = o;
    }
  }
}

// ---------------- v-patch matrix gather: vp[n][l][ (i*5+j)*64 + b ] ----------------
__global__ void vp_gather(const float* __restrict__ vfea, float* __restrict__ vp) {
  const int bij = blockIdx.x * 256 + threadIdx.x;
  const int l = blockIdx.y, n = blockIdx.z;
  if (bij >= NPAD) return;
  const int ij = bij >> 6, b = bij & 63;
  float val = 0.f;
  if (ij < 25) {
    const int i = ij / 5, j = ij % 5;
    const int ly = l >> 4, lx = l & 15;
    const int r = 4 * ly + i, c = 4 * lx + j;
    if (r < HK && c < HK) val = vfea[((size_t)(n * COC + b) * HK + r) * HK + c];
  }
  vp[((size_t)(n * LL + l)) * NPAD + bij] = val;
}

// ---------------- PV GEMM: C[4096][NPAD] = A[4096][256] * B[256][NPAD] ----------------
__global__ __launch_bounds__(256) void pv_gemm(
    const float* __restrict__ A, const float* __restrict__ Bm, float* __restrict__ C) {
  const int m0 = blockIdx.x * 128;
  const int n0 = blockIdx.y * 128;
  const int tid = threadIdx.x;
  const int tm = tid & 15, tn = tid >> 4;
  __shared__ float As[16][132];
  __shared__ float Bs[16][128];
  float acc[8][8];
  #pragma unroll
  for (int a = 0; a < 8; ++a)
    #pragma unroll
    for (int b = 0; b < 8; ++b) acc[a][b] = 0.f;

  for (int k0 = 0; k0 < 256; k0 += 16) {
    __syncthreads();
    #pragma unroll
    for (int r = 0; r < 2; ++r) {
      const int idx = tid + r * 256;
      const int row = idx >> 2, c4 = idx & 3;
      const float4 v = *(const float4*)&A[(size_t)(m0 + row) * 256 + k0 + c4 * 4];
      As[c4 * 4 + 0][row] = v.x;
      As[c4 * 4 + 1][row] = v.y;
      As[c4 * 4 + 2][row] = v.z;
      As[c4 * 4 + 3][row] = v.w;
    }
    #pragma unroll
    for (int r = 0; r < 2; ++r) {
      const int idx = tid + r * 256;
      const int row = idx >> 5, c4 = idx & 31;
      *(float4*)&Bs[row][c4 * 4] = *(const float4*)&Bm[(size_t)(k0 + row) * NPAD + n0 + c4 * 4];
    }
    __syncthreads();
    #pragma unroll
    for (int k = 0; k < 16; ++k) {
      const float4 a0 = *(const float4*)&As[k][tm * 8];
      const float4 a1 = *(const float4*)&As[k][tm * 8 + 4];
      const float4 b0 = *(const float4*)&Bs[k][tn * 8];
      const float4 b1 = *(const float4*)&Bs[k][tn * 8 + 4];
      const float av[8] = {a0.x, a0.y, a0.z, a0.w, a1.x, a1.y, a1.z, a1.w};
      const float bv[8] = {b0.x, b0.y, b0.z, b0.w, b1.x, b1.y, b1.z, b1.w};
      #pragma unroll
      for (int mi = 0; mi < 8; ++mi)
        #pragma unroll
        for (int ni = 0; ni < 8; ++ni)
          acc[mi][ni] = fmaf(av[mi], bv[ni], acc[mi][ni]);
    }
  }
  #pragma unroll
  for (int mi = 0; mi < 8; ++mi) {
    float* dst = &C[(size_t)(m0 + tm * 8 + mi) * NPAD + n0 + tn * 8];
    *(float4*)dst = make_float4(acc[mi][0], acc[mi][1], acc[mi][2], acc[mi][3]);
    *(float4*)(dst + 4) = make_float4(acc[mi][4], acc[mi][5], acc[mi][6], acc[mi][7]);
  }
}

// ---------------- conv-transpose contribution gather (+ /6) ----------------
// grid (4 xt, 256 y); block 256; per-batch n.
__global__ __launch_bounds__(256) void u_scatter(
    const float* __restrict__ U, float* __restrict__ res, int n) {
  const int y = blockIdx.y;
  const int xt = blockIdx.x;
  const int tid = threadIdx.x;
  __shared__ float t_lds[64][65];
  const int ym = (y + 1) >> 2, yr = (y + 1) & 3;
  const bool v0 = (ym < 64);
  const bool v1 = (yr == 0 && ym >= 1);
  const int b = tid & 63, xg = tid >> 6;
  for (int xi = 0; xi < 16; ++xi) {
    const int x = xt * 64 + xg * 16 + xi;
    const int xm = (x + 1) >> 2, xr = (x + 1) & 3;
    const bool u0 = (xm < 64);
    const bool u1 = (xr == 0 && xm >= 1);
    float s = 0.f;
    if (v0) {
      const size_t rb = (size_t)(ym * 64) * NPAD;
      if (u0) s += U[rb + (size_t)xm * NPAD + (yr * 5 + xr) * 64 + b];
      if (u1) s += U[rb + (size_t)(xm - 1) * NPAD + (yr * 5 + 4) * 64 + b];
    }
    if (v1) {
      const size_t rb = (size_t)((ym - 1) * 64) * NPAD;
      if (u0) s += U[rb + (size_t)xm * NPAD + (4 * 5 + xr) * 64 + b];
      if (u1) s += U[rb + (size_t)(xm - 1) * NPAD + (4 * 5 + 4) * 64 + b];
    }
    t_lds[xg * 16 + xi][b] = s * (1.0f / 6.0f);
  }
  __syncthreads();
  const int xl = tid & 63, bg = tid >> 6;
  for (int bb = 0; bb < 16; ++bb) {
    const int bc = bg * 16 + bb;
    res[((size_t)(n * COC + bc) * HQ + y) * HQ + xt * 64 + xl] = t_lds[xl][bc];
  }
}

extern "C" void kernel_launch(void* const* d_in, const int* in_sizes, int n_in,
                              void* d_out, int out_size, void* d_ws, size_t ws_size,
                              hipStream_t stream) {
  const float* ms   = (const float*)d_in[0];
  const float* pan  = (const float*)d_in[1];
  const float* pan2 = (const float*)d_in[2];
  const float* Wq   = (const float*)d_in[3];
  const float* bq   = (const float*)d_in[4];
  const float* Wk   = (const float*)d_in[5];
  const float* bk   = (const float*)d_in[6];
  const float* Wv   = (const float*)d_in[7];
  const float* bv   = (const float*)d_in[8];
  const float* Wr   = (const float*)d_in[9];
  const float* br   = (const float*)d_in[10];
  float* out = (float*)d_out;

  float* ws = (float*)d_ws;
  const size_t SZ_Q  = (size_t)NB * COC * HQ * HQ;  // 33.5M elem (q_fea, reused as res)
  const size_t SZ_K  = (size_t)NB * CI * HK * HK;   // 2.1M elem
  const size_t SZ_WN = (size_t)NB * 64 * 64 * LL;   // 8.4M elem (exact)
  float* q_fea  = ws;
  float* k_fea  = q_fea + SZ_Q;
  float* v_fea  = k_fea + SZ_K;
  float* wn     = v_fea + SZ_K;
  float* vp     = wn + SZ_WN;
  float* U      = vp + (size_t)NB * LL * NPAD;
  float* norms  = U + (size_t)4096 * NPAD;
  float* kscale = norms + NB * LL;
  float* res    = q_fea;  // q_fea dead after qk_softmax

  // feature convs
  conv3_lrelu<<<dim3(1, HK / 16, NB * COC), dim3(16, 16), 0, stream>>>(pan2, Wk, bk, k_fea, HK, HK);
  conv3_lrelu<<<dim3(1, HK / 16, NB * COC), dim3(16, 16), 0, stream>>>(ms,   Wv, bv, v_fea, HK, HK);
  conv3_lrelu<<<dim3(1, HQ / 4,  NB * COC), dim3(64, 4),  0, stream>>>(pan,  Wq, bq, q_fea, HQ, HQ);

  // k-patch max norm -> scale
  knorm_kernel<<<dim3(LL, NB), 64, 0, stream>>>(k_fea, norms);
  kscale_kernel<<<NB, 256, 0, stream>>>(norms, kscale);

  // attention weights
  qk_softmax<<<dim3(64, NB), 256, 0, stream>>>(q_fea, k_fea, kscale, wn);

  // v patch matrix
  vp_gather<<<dim3((NPAD + 255) / 256, LL, NB), 256, 0, stream>>>(v_fea, vp);

  // per-batch PV GEMM + conv-transpose gather
  for (int n = 0; n < NB; ++n) {
    pv_gemm<<<dim3(32, 13), 256, 0, stream>>>(wn + (size_t)n * 4096 * 256,
                                              vp + (size_t)n * LL * NPAD, U);
    u_scatter<<<dim3(4, HQ), 256, 0, stream>>>(U, res, n);
  }

  // final conv
  conv3_lrelu<<<dim3(1, HQ / 4, NB * COC), dim3(64, 4), 0, stream>>>(res, Wr, br, out, HQ, HQ);
}

// Round 4
// 4122.280 us; speedup vs baseline: 2.3278x; 2.3278x over previous
//
#include <hip/hip_runtime.h>
#include <math.h>

#define NB   8
#define CI   64
#define COC  64
#define HQ   256
#define HK   64
#define KS   5
#define LL   256
#define NPAD 1664

// ---------------- weight transpose: [CO][CI][3][3] -> [CI][tap][CO] ----------------
// grid (9, 64), block 64
__global__ void wtrans_kernel(const float* __restrict__ Wt, float* __restrict__ Wo) {
  const int co = threadIdx.x;   // 0..63
  const int tap = blockIdx.x;   // 0..8
  const int ci = blockIdx.y;    // 0..63
  Wo[(ci * 9 + tap) * 64 + co] = Wt[(co * 64 + ci) * 9 + tap];
}

// ---------------- conv 3x3 pad1 + bias + leaky relu, register/LDS tiled ----------------
// block tile: 32x X 16y X 32co. grid (Wd/32, H/16, NB*2). 256 threads.
// thread: xq=tid&7 (4 px), yt=(tid>>3)&7 (2 rows), cg=tid>>6 (8 co; wave-uniform)
__global__ __launch_bounds__(256, 4) void conv3_tile(
    const float* __restrict__ in, const float* __restrict__ Wts /*[CI][9][CO]*/,
    const float* __restrict__ bias, float* __restrict__ out, int H, int Wd) {
  const int x0 = blockIdx.x * 32;
  const int y0 = blockIdx.y * 16;
  const int z  = blockIdx.z;
  const int n  = z >> 1;
  const int cob = (z & 1) * 32;
  const int tid = threadIdx.x;
  const int xq = tid & 7;
  const int yt = (tid >> 3) & 7;
  const int cg = tid >> 6;

  __shared__ float in_s[18 * 37];
  __shared__ float w_s[9 * 32];

  float acc[8][2][4];
  #pragma unroll
  for (int a = 0; a < 8; ++a)
    #pragma unroll
    for (int b = 0; b < 2; ++b)
      #pragma unroll
      for (int c = 0; c < 4; ++c) acc[a][b][c] = 0.f;

  const float* ib = in + (size_t)n * CI * H * Wd;

  for (int ci = 0; ci < CI; ++ci) {
    __syncthreads();
    // stage 18x37 input tile (halo 1, zero-padded at image edges)
    const float* plane = ib + (size_t)ci * H * Wd;
    #pragma unroll
    for (int k = 0; k < 3; ++k) {
      const int idx = tid + k * 256;
      if (idx < 666) {
        const int r = (idx * 886) >> 15;   // idx/37, exact for idx<666
        const int c = idx - r * 37;
        const int gy = y0 + r - 1, gx = x0 + c - 1;
        float v = 0.f;
        if (gy >= 0 && gy < H && gx >= 0 && gx < Wd) v = plane[gy * Wd + gx];
        in_s[r * 37 + c] = v;
      }
    }
    // stage weights for this ci: 9 taps x 32 co (coalesced from [ci][tap][64])
    {
      const float* wp = Wts + (size_t)ci * 9 * 64 + cob;
      #pragma unroll
      for (int k = 0; k < 2; ++k) {
        const int idx = tid + k * 256;
        if (idx < 288) {
          const int tap = idx >> 5, col = idx & 31;
          w_s[idx] = wp[tap * 64 + col];
        }
      }
    }
    __syncthreads();

    // load my 4 rows x 6 cols into registers
    float xin[4][6];
    const int rb = yt * 2, cb = xq * 4;
    #pragma unroll
    for (int r = 0; r < 4; ++r)
      #pragma unroll
      for (int c = 0; c < 6; ++c)
        xin[r][c] = in_s[(rb + r) * 37 + cb + c];

    #pragma unroll
    for (int tap = 0; tap < 9; ++tap) {
      const int ky = tap / 3, kx = tap % 3;
      const float4 w0 = *(const float4*)&w_s[tap * 32 + cg * 8];
      const float4 w1 = *(const float4*)&w_s[tap * 32 + cg * 8 + 4];
      const float wv[8] = {w0.x, w0.y, w0.z, w0.w, w1.x, w1.y, w1.z, w1.w};
      #pragma unroll
      for (int c8 = 0; c8 < 8; ++c8)
        #pragma unroll
        for (int dy = 0; dy < 2; ++dy)
          #pragma unroll
          for (int dx = 0; dx < 4; ++dx)
            acc[c8][dy][dx] = fmaf(wv[c8], xin[dy + ky][dx + kx], acc[c8][dy][dx]);
    }
  }

  // epilogue: bias + leaky relu, float4 stores
  #pragma unroll
  for (int c8 = 0; c8 < 8; ++c8) {
    const int co = cob + cg * 8 + c8;
    const float bv = bias[co];
    #pragma unroll
    for (int dy = 0; dy < 2; ++dy) {
      float4 o;
      float t;
      t = acc[c8][dy][0] + bv; o.x = t > 0.f ? t : 0.01f * t;
      t = acc[c8][dy][1] + bv; o.y = t > 0.f ? t : 0.01f * t;
      t = acc[c8][dy][2] + bv; o.z = t > 0.f ? t : 0.01f * t;
      t = acc[c8][dy][3] + bv; o.w = t > 0.f ? t : 0.01f * t;
      *(float4*)(out + ((size_t)(n * COC + co) * H + y0 + yt * 2 + dy) * Wd + x0 + xq * 4) = o;
    }
  }
}

// ---------------- k-patch squared norms ----------------
__global__ void knorm_kernel(const float* __restrict__ kfea, float* __restrict__ norms) {
  const int l = blockIdx.x, n = blockIdx.y, c = threadIdx.x;
  const int ly = l >> 4, lx = l & 15;
  const float* base = kfea + ((size_t)(n * CI + c) * HK) * HK;
  float ss = 0.f;
  #pragma unroll
  for (int i = 0; i < KS; ++i) {
    const int r = 4 * ly + i;
    if (r >= HK) continue;
    #pragma unroll
    for (int j = 0; j < KS; ++j) {
      const int cc = 4 * lx + j;
      if (cc >= HK) continue;
      const float v = base[r * HK + cc];
      ss = fmaf(v, v, ss);
    }
  }
  for (int off = 32; off; off >>= 1) ss += __shfl_down(ss, off);
  if (c == 0) norms[n * LL + l] = ss;
}

__global__ void kscale_kernel(const float* __restrict__ norms, float* __restrict__ kscale) {
  const int n = blockIdx.x, t = threadIdx.x;
  float v = norms[n * LL + t];
  for (int off = 32; off; off >>= 1) v = fmaxf(v, __shfl_down(v, off));
  __shared__ float red[4];
  if ((t & 63) == 0) red[t >> 6] = v;
  __syncthreads();
  if (t == 0) {
    const float m = fmaxf(fmaxf(red[0], red[1]), fmaxf(red[2], red[3]));
    kscale[n] = 10.0f / sqrtf(m);
  }
}

// ---------------- fused QK correlation + softmax ----------------
__global__ __launch_bounds__(256) void qk_softmax(
    const float* __restrict__ qfea, const float* __restrict__ kfea,
    const float* __restrict__ kscale, float* __restrict__ wn) {
  const int h = blockIdx.x, n = blockIdx.y;
  const int tid = threadIdx.x;
  const int lt = tid >> 4;
  const int wt = tid & 15;
  __shared__ float k_s[25 * 16 * 16];
  __shared__ float q_s[25 * 64];
  __shared__ float red[64 * 17];
  float acc[16][4];
  #pragma unroll
  for (int a = 0; a < 16; ++a)
    #pragma unroll
    for (int b = 0; b < 4; ++b) acc[a][b] = 0.f;

  const float* kb = kfea + (size_t)n * CI * HK * HK;
  const float* qb = qfea + (size_t)n * CI * HQ * HQ;

  for (int ci = 0; ci < CI; ++ci) {
    __syncthreads();
    for (int s = tid; s < 25 * 256; s += 256) {
      const int lx = s & 15, ly = (s >> 4) & 15, ij = s >> 8;
      const int i = ij / 5, j = ij % 5;
      const int r = 4 * ly + i, c = 4 * lx + j;
      k_s[s] = (r < HK && c < HK) ? kb[((size_t)ci * HK + r) * HK + c] : 0.f;
    }
    for (int s = tid; s < 25 * 64; s += 256) {
      const int w = s & 63, ij = s >> 6;
      const int i = ij / 5, j = ij % 5;
      const int gr = 4 * h + i, gc = 4 * w + j;
      q_s[s] = (gr < HQ && gc < HQ) ? qb[((size_t)ci * HQ + gr) * HQ + gc] : 0.f;
    }
    __syncthreads();
    #pragma unroll 5
    for (int ij = 0; ij < 25; ++ij) {
      const float4 q4 = *(const float4*)&q_s[ij * 64 + wt * 4];
      const float4* kp4 = (const float4*)&k_s[(ij * 16 + lt) * 16];
      const float4 k0 = kp4[0], k1 = kp4[1], k2 = kp4[2], k3 = kp4[3];
      const float kk[16] = {k0.x, k0.y, k0.z, k0.w, k1.x, k1.y, k1.z, k1.w,
                            k2.x, k2.y, k2.z, k2.w, k3.x, k3.y, k3.z, k3.w};
      const float qq[4] = {q4.x, q4.y, q4.z, q4.w};
      #pragma unroll
      for (int li = 0; li < 16; ++li)
        #pragma unroll
        for (int ww = 0; ww < 4; ++ww)
          acc[li][ww] = fmaf(kk[li], qq[ww], acc[li][ww]);
    }
  }

  const float f = kscale[n];
  #pragma unroll
  for (int li = 0; li < 16; ++li)
    #pragma unroll
    for (int ww = 0; ww < 4; ++ww) acc[li][ww] *= f;

  #pragma unroll
  for (int ww = 0; ww < 4; ++ww) {
    float m = acc[0][ww];
    #pragma unroll
    for (int li = 1; li < 16; ++li) m = fmaxf(m, acc[li][ww]);
    red[(wt * 4 + ww) * 17 + lt] = m;
  }
  __syncthreads();
  if (tid < 64) {
    float m = red[tid * 17];
    #pragma unroll
    for (int k = 1; k < 16; ++k) m = fmaxf(m, red[tid * 17 + k]);
    red[tid * 17 + 16] = m;
  }
  __syncthreads();
  float sloc[4];
  #pragma unroll
  for (int ww = 0; ww < 4; ++ww) {
    const float m = red[(wt * 4 + ww) * 17 + 16];
    float s = 0.f;
    #pragma unroll
    for (int li = 0; li < 16; ++li) {
      const float e = __expf(acc[li][ww] - m);
      acc[li][ww] = e;
      s += e;
    }
    sloc[ww] = s;
  }
  __syncthreads();
  #pragma unroll
  for (int ww = 0; ww < 4; ++ww) red[(wt * 4 + ww) * 17 + lt] = sloc[ww];
  __syncthreads();
  if (tid < 64) {
    float s = red[tid * 17];
    #pragma unroll
    for (int k = 1; k < 16; ++k) s += red[tid * 17 + k];
    red[tid * 17 + 16] = s;
  }
  __syncthreads();
  #pragma unroll
  for (int ww = 0; ww < 4; ++ww) {
    const int w = wt * 4 + ww;
    const float inv = 1.0f / red[w * 17 + 16];
    float* dst = wn + (((size_t)(n * 64 + h) * 64 + w) * 256) + lt * 16;
    #pragma unroll
    for (int q = 0; q < 4; ++q) {
      float4 o = make_float4(acc[q * 4 + 0][ww] * inv, acc[q * 4 + 1][ww] * inv,
                             acc[q * 4 + 2][ww] * inv, acc[q * 4 + 3][ww] * inv);
      *(float4*)(dst + q * 4) = o;
    }
  }
}

// ---------------- v-patch matrix gather ----------------
__global__ void vp_gather(const float* __restrict__ vfea, float* __restrict__ vp) {
  const int bij = blockIdx.x * 256 + threadIdx.x;
  const int l = blockIdx.y, n = blockIdx.z;
  if (bij >= NPAD) return;
  const int ij = bij >> 6, b = bij & 63;
  float val = 0.f;
  if (ij < 25) {
    const int i = ij / 5, j = ij % 5;
    const int ly = l >> 4, lx = l & 15;
    const int r = 4 * ly + i, c = 4 * lx + j;
    if (r < HK && c < HK) val = vfea[((size_t)(n * COC + b) * HK + r) * HK + c];
  }
  vp[((size_t)(n * LL + l)) * NPAD + bij] = val;
}

// ---------------- PV GEMM (z = batch) ----------------
__global__ __launch_bounds__(256) void pv_gemm(
    const float* __restrict__ A0, const float* __restrict__ B0, float* __restrict__ C0) {
  const int nz = blockIdx.z;
  const float* A = A0 + (size_t)nz * 4096 * 256;
  const float* Bm = B0 + (size_t)nz * LL * NPAD;
  float* C = C0 + (size_t)nz * 4096 * NPAD;
  const int m0 = blockIdx.x * 128;
  const int n0 = blockIdx.y * 128;
  const int tid = threadIdx.x;
  const int tm = tid & 15, tn = tid >> 4;
  __shared__ float As[16][132];
  __shared__ float Bs[16][128];
  float acc[8][8];
  #pragma unroll
  for (int a = 0; a < 8; ++a)
    #pragma unroll
    for (int b = 0; b < 8; ++b) acc[a][b] = 0.f;

  for (int k0 = 0; k0 < 256; k0 += 16) {
    __syncthreads();
    #pragma unroll
    for (int r = 0; r < 2; ++r) {
      const int idx = tid + r * 256;
      const int row = idx >> 2, c4 = idx & 3;
      const float4 v = *(const float4*)&A[(size_t)(m0 + row) * 256 + k0 + c4 * 4];
      As[c4 * 4 + 0][row] = v.x;
      As[c4 * 4 + 1][row] = v.y;
      As[c4 * 4 + 2][row] = v.z;
      As[c4 * 4 + 3][row] = v.w;
    }
    #pragma unroll
    for (int r = 0; r < 2; ++r) {
      const int idx = tid + r * 256;
      const int row = idx >> 5, c4 = idx & 31;
      *(float4*)&Bs[row][c4 * 4] = *(const float4*)&Bm[(size_t)(k0 + row) * NPAD + n0 + c4 * 4];
    }
    __syncthreads();
    #pragma unroll
    for (int k = 0; k < 16; ++k) {
      const float4 a0 = *(const float4*)&As[k][tm * 8];
      const float4 a1 = *(const float4*)&As[k][tm * 8 + 4];
      const float4 b0 = *(const float4*)&Bs[k][tn * 8];
      const float4 b1 = *(const float4*)&Bs[k][tn * 8 + 4];
      const float av[8] = {a0.x, a0.y, a0.z, a0.w, a1.x, a1.y, a1.z, a1.w};
      const float bv[8] = {b0.x, b0.y, b0.z, b0.w, b1.x, b1.y, b1.z, b1.w};
      #pragma unroll
      for (int mi = 0; mi < 8; ++mi)
        #pragma unroll
        for (int ni = 0; ni < 8; ++ni)
          acc[mi][ni] = fmaf(av[mi], bv[ni], acc[mi][ni]);
    }
  }
  #pragma unroll
  for (int mi = 0; mi < 8; ++mi) {
    float* dst = &C[(size_t)(m0 + tm * 8 + mi) * NPAD + n0 + tn * 8];
    *(float4*)dst = make_float4(acc[mi][0], acc[mi][1], acc[mi][2], acc[mi][3]);
    *(float4*)(dst + 4) = make_float4(acc[mi][4], acc[mi][5], acc[mi][6], acc[mi][7]);
  }
}

// ---------------- conv-transpose contribution gather (+ /6) ----------------
// grid (4 xt, 256 y, nz); n = n0 + blockIdx.z
__global__ __launch_bounds__(256) void u_scatter(
    const float* __restrict__ U0, float* __restrict__ res, int n0) {
  const int n = n0 + blockIdx.z;
  const float* U = U0 + (size_t)blockIdx.z * 4096 * NPAD;
  const int y = blockIdx.y;
  const int xt = blockIdx.x;
  const int tid = threadIdx.x;
  __shared__ float t_lds[64][65];
  const int ym = (y + 1) >> 2, yr = (y + 1) & 3;
  const bool v0 = (ym < 64);
  const bool v1 = (yr == 0 && ym >= 1);
  const int b = tid & 63, xg = tid >> 6;
  for (int xi = 0; xi < 16; ++xi) {
    const int x = xt * 64 + xg * 16 + xi;
    const int xm = (x + 1) >> 2, xr = (x + 1) & 3;
    const bool u0 = (xm < 64);
    const bool u1 = (xr == 0 && xm >= 1);
    float s = 0.f;
    if (v0) {
      const size_t rb = (size_t)(ym * 64) * NPAD;
      if (u0) s += U[rb + (size_t)xm * NPAD + (yr * 5 + xr) * 64 + b];
      if (u1) s += U[rb + (size_t)(xm - 1) * NPAD + (yr * 5 + 4) * 64 + b];
    }
    if (v1) {
      const size_t rb = (size_t)((ym - 1) * 64) * NPAD;
      if (u0) s += U[rb + (size_t)xm * NPAD + (4 * 5 + xr) * 64 + b];
      if (u1) s += U[rb + (size_t)(xm - 1) * NPAD + (4 * 5 + 4) * 64 + b];
    }
    t_lds[xg * 16 + xi][b] = s * (1.0f / 6.0f);
  }
  __syncthreads();
  const int xl = tid & 63, bg = tid >> 6;
  for (int bb = 0; bb < 16; ++bb) {
    const int bc = bg * 16 + bb;
    res[((size_t)(n * COC + bc) * HQ + y) * HQ + xt * 64 + xl] = t_lds[xl][bc];
  }
}

extern "C" void kernel_launch(void* const* d_in, const int* in_sizes, int n_in,
                              void* d_out, int out_size, void* d_ws, size_t ws_size,
                              hipStream_t stream) {
  const float* ms   = (const float*)d_in[0];
  const float* pan  = (const float*)d_in[1];
  const float* pan2 = (const float*)d_in[2];
  const float* Wq   = (const float*)d_in[3];
  const float* bq   = (const float*)d_in[4];
  const float* Wk   = (const float*)d_in[5];
  const float* bk   = (const float*)d_in[6];
  const float* Wv   = (const float*)d_in[7];
  const float* bv   = (const float*)d_in[8];
  const float* Wr   = (const float*)d_in[9];
  const float* br   = (const float*)d_in[10];
  float* out = (float*)d_out;

  float* ws = (float*)d_ws;
  const size_t SZ_Q  = (size_t)NB * COC * HQ * HQ;   // 33.55M
  const size_t SZ_K  = (size_t)NB * CI * HK * HK;    // 2.10M
  const size_t SZ_WN = (size_t)NB * 64 * 64 * LL;    // 8.39M
  const size_t SZ_VP = (size_t)NB * LL * NPAD;       // 3.41M
  const size_t SZ_U1 = (size_t)4096 * NPAD;          // 6.82M per batch
  float* q_fea  = ws;
  float* k_fea  = q_fea + SZ_Q;
  float* v_fea  = k_fea + SZ_K;
  float* wn     = v_fea + SZ_K;
  float* vp     = wn + SZ_WN;
  float* norms  = vp + SZ_VP;
  float* kscale = norms + NB * LL;
  float* wtq    = kscale + 64;          // 4 transposed weights, 36864 each
  float* wtk    = wtq + 36864;
  float* wtv    = wtk + 36864;
  float* wtr    = wtv + 36864;
  float* U      = wtr + 36864;
  float* res    = q_fea;  // q_fea dead after qk_softmax

  const size_t base_elems = (size_t)(U - ws);
  const bool batched = ws_size >= (base_elems + (size_t)NB * SZ_U1) * sizeof(float);

  // weight transposes
  wtrans_kernel<<<dim3(9, 64), 64, 0, stream>>>(Wq, wtq);
  wtrans_kernel<<<dim3(9, 64), 64, 0, stream>>>(Wk, wtk);
  wtrans_kernel<<<dim3(9, 64), 64, 0, stream>>>(Wv, wtv);
  wtrans_kernel<<<dim3(9, 64), 64, 0, stream>>>(Wr, wtr);

  // feature convs
  conv3_tile<<<dim3(HK / 32, HK / 16, NB * 2), 256, 0, stream>>>(pan2, wtk, bk, k_fea, HK, HK);
  conv3_tile<<<dim3(HK / 32, HK / 16, NB * 2), 256, 0, stream>>>(ms,   wtv, bv, v_fea, HK, HK);
  conv3_tile<<<dim3(HQ / 32, HQ / 16, NB * 2), 256, 0, stream>>>(pan,  wtq, bq, q_fea, HQ, HQ);

  // k-patch max norm -> scale
  knorm_kernel<<<dim3(LL, NB), 64, 0, stream>>>(k_fea, norms);
  kscale_kernel<<<NB, 256, 0, stream>>>(norms, kscale);

  // attention weights
  qk_softmax<<<dim3(64, NB), 256, 0, stream>>>(q_fea, k_fea, kscale, wn);

  // v patch matrix
  vp_gather<<<dim3((NPAD + 255) / 256, LL, NB), 256, 0, stream>>>(v_fea, vp);

  if (batched) {
    pv_gemm<<<dim3(32, 13, NB), 256, 0, stream>>>(wn, vp, U);
    u_scatter<<<dim3(4, HQ, NB), 256, 0, stream>>>(U, res, 0);
  } else {
    for (int n = 0; n < NB; ++n) {
      pv_gemm<<<dim3(32, 13, 1), 256, 0, stream>>>(wn + (size_t)n * 4096 * 256,
                                                   vp + (size_t)n * LL * NPAD, U);
      u_scatter<<<dim3(4, HQ, 1), 256, 0, stream>>>(U, res, n);
    }
  }

  // final conv
  conv3_tile<<<dim3(HQ / 32, HQ / 16, NB * 2), 256, 0, stream>>>(res, wtr, br, out, HQ, HQ);
}